// Round 6
// baseline (469.295 us; speedup 1.0000x reference)
//
#include <hip/hip_runtime.h>
#include <stdint.h>

typedef unsigned short ushort_t;
typedef __attribute__((ext_vector_type(8))) short short8;     // 8 x bf16 (MFMA A/B frag)
typedef __attribute__((ext_vector_type(4))) float floatx4;    // MFMA C/D frag / 16B fp32 vector
typedef __attribute__((ext_vector_type(4))) unsigned int u32x4; // 16B vector

__device__ __forceinline__ float bf2f(ushort_t u) {
    union { unsigned int i; float f; } v; v.i = ((unsigned int)u) << 16; return v.f;
}
__device__ __forceinline__ ushort_t f2bf(float f) {
    union { float ff; unsigned int i; } v; v.ff = f;
    unsigned int x = v.i;
    return (ushort_t)((x + 0x7fffu + ((x >> 16) & 1u)) >> 16);  // RNE
}
// tanh-form GELU (max |err| vs exact-erf GELU ~1e-3, negligible vs 0.3275 threshold)
__device__ __forceinline__ float gelu_f(float v) {
    float u = v * (0.7978845608f + 0.0356774081f * v * v);
    float e = __expf(2.f * u);
    float th = 1.f - 2.f / (e + 1.f);    // tanh(u)
    return 0.5f * v * (1.f + th);
}
#define LDS_ROUNDTRIP_FENCE() __asm__ volatile("s_waitcnt lgkmcnt(0)" ::: "memory")

// ---------------- K0: weight transpose fp32 [R][C] -> bf16 [C][R] ----------------
__global__ __launch_bounds__(256) void transpose_k(const float* __restrict__ src,
                                                   ushort_t* __restrict__ dst, int R, int C) {
    __shared__ float t[16][17];
    int tx = threadIdx.x & 15, ty = threadIdx.x >> 4;
    int c0 = blockIdx.x * 16, r0 = blockIdx.y * 16;
    t[ty][tx] = src[(size_t)(r0 + ty) * C + (c0 + tx)];
    __syncthreads();
    dst[(size_t)(c0 + ty) * R + (r0 + tx)] = f2bf(t[tx][ty]);
}

// ---------------- w1prep: w1 fp32 [256][1024] -> w1p bf16 [16][64][264] ----------------
__global__ __launch_bounds__(256) void w1prep_k(const float* __restrict__ src,
                                                ushort_t* __restrict__ dst) {
    __shared__ float s[64][65];
    const int ch = blockIdx.x, k0 = blockIdx.y * 64;
    const int t = threadIdx.x;
    {
        int nn = t & 63, kr = t >> 6;
        for (int j = 0; j < 16; ++j) {
            int kk = j * 4 + kr;
            s[kk][nn] = src[(size_t)(k0 + kk) * 1024 + ch * 64 + nn];
        }
    }
    __syncthreads();
    {
        int kk = t & 63, nr = t >> 6;
        for (int j = 0; j < 16; ++j) {
            int n2 = j * 4 + nr;
            dst[(size_t)ch * 16896 + n2 * 264 + k0 + kk] = f2bf(s[kk][n2]);
        }
    }
}

// ---------------- w2prep: w2 fp32 [1024][256] -> w2p bf16 [16][256][72] ----------------
__global__ __launch_bounds__(256) void w2prep_k(const float* __restrict__ src,
                                                ushort_t* __restrict__ dst) {
    __shared__ float s[64][65];
    const int ch = blockIdx.x, n0 = blockIdx.y * 64;
    const int t = threadIdx.x;
    {
        int nn = t & 63, kr = t >> 6;
        for (int j = 0; j < 16; ++j) {
            int kk = j * 4 + kr;
            s[kk][nn] = src[(size_t)(ch * 64 + kk) * 256 + n0 + nn];
        }
    }
    __syncthreads();
    {
        int kk = t & 63, nr = t >> 6;
        for (int j = 0; j < 16; ++j) {
            int n2 = j * 4 + nr;
            dst[(size_t)ch * 18432 + (n0 + n2) * 72 + kk] = f2bf(s[kk][n2]);
        }
    }
}

// ---------------- K1: LN1 + NCHW(fp32)->NHWC(bf16) transpose ----------------
__global__ __launch_bounds__(256) void ln1_k(const float* __restrict__ x,
                                             const float* __restrict__ g,
                                             const float* __restrict__ b,
                                             ushort_t* __restrict__ xn) {
    __shared__ ushort_t tile[64 * 264];
    const int t = threadIdx.x;
    const int p0 = blockIdx.x * 64;
    {
        const int pg = t & 15;
        const int cb = t >> 4;
        for (int it = 0; it < 16; ++it) {
            int c = cb + 16 * it;
            floatx4 v = *(const floatx4*)(x + (size_t)c * 65536 + p0 + pg * 4);
            #pragma unroll
            for (int k = 0; k < 4; ++k) tile[(pg * 4 + k) * 264 + c] = f2bf(v[k]);
        }
    }
    __syncthreads();
    const int pix = t >> 2, part = t & 3;
    float vals[64];
    float s = 0.f, ss = 0.f;
    #pragma unroll
    for (int k = 0; k < 64; ++k) {
        float v = bf2f(tile[pix * 264 + part * 64 + k]);
        vals[k] = v; s += v; ss += v * v;
    }
    s  += __shfl_xor(s, 1);  s  += __shfl_xor(s, 2);
    ss += __shfl_xor(ss, 1); ss += __shfl_xor(ss, 2);
    float mean = s * (1.f / 256.f);
    float rstd = rsqrtf(ss * (1.f / 256.f) - mean * mean + 1e-5f);
    size_t obase = (size_t)(p0 + pix) * 256 + part * 64;
    #pragma unroll
    for (int k8 = 0; k8 < 8; ++k8) {
        alignas(16) ushort_t o8[8];
        #pragma unroll
        for (int k = 0; k < 8; ++k) {
            int c = part * 64 + k8 * 8 + k;
            o8[k] = f2bf((vals[k8 * 8 + k] - mean) * rstd * g[c] + b[c]);
        }
        *(u32x4*)(xn + obase + k8 * 8) = *(const u32x4*)o8;
    }
}

// ---------------- K2a: dense QKV GEMM for one (image-half, branch) ----------------
// qkvbuf[tl][0:128]=q, [128:256]=k, [256:384]=v for local tokens tl in 0..32767.
__global__ __launch_bounds__(512, 4) void qkv_half_k(
    const ushort_t* __restrict__ xn,      // [65536][256] bf16
    const ushort_t* __restrict__ wqkvT,   // [384][128] bf16
    ushort_t* __restrict__ qkvbuf,        // [32768][384] bf16
    int p_base, int chOff)
{
    __shared__ __align__(16) ushort_t a_s[128 * 136];
    __shared__ __align__(16) ushort_t b_s[128 * 136];
    const int t = threadIdx.x;
    const int m0 = blockIdx.x * 128;      // local token base
    const int n0 = blockIdx.y * 128;      // qkv column base
    const int wv = t >> 6, lane = t & 63, l15 = lane & 15, quad = lane >> 4;

    {   // stage A (xn half-channel tile) and B (weight tile), both coalesced
        int row = t >> 2, seg = t & 3;
        const ushort_t* sa = xn + (size_t)(p_base + m0 + row) * 256 + chOff + seg * 32;
        ushort_t* da = a_s + row * 136 + seg * 32;
        *(u32x4*)(da)      = *(const u32x4*)(sa);
        *(u32x4*)(da + 8)  = *(const u32x4*)(sa + 8);
        *(u32x4*)(da + 16) = *(const u32x4*)(sa + 16);
        *(u32x4*)(da + 24) = *(const u32x4*)(sa + 24);
        const ushort_t* sb = wqkvT + (size_t)(n0 + row) * 128 + seg * 32;
        ushort_t* db = b_s + row * 136 + seg * 32;
        *(u32x4*)(db)      = *(const u32x4*)(sb);
        *(u32x4*)(db + 8)  = *(const u32x4*)(sb + 8);
        *(u32x4*)(db + 16) = *(const u32x4*)(sb + 16);
        *(u32x4*)(db + 24) = *(const u32x4*)(sb + 24);
    }
    __syncthreads();

    const int g = wv & 3, h = wv >> 2;    // wave: rows 32g..32g+31, cols 64h..64h+63
    floatx4 acc[2][4];
    #pragma unroll
    for (int mi = 0; mi < 2; ++mi)
        #pragma unroll
        for (int nj = 0; nj < 4; ++nj) acc[mi][nj] = floatx4{0.f, 0.f, 0.f, 0.f};
    #pragma unroll
    for (int kt = 0; kt < 4; ++kt) {
        short8 af[2], bf[4];
        #pragma unroll
        for (int mi = 0; mi < 2; ++mi)
            af[mi] = *(const short8*)(a_s + (32 * g + 16 * mi + l15) * 136 + kt * 32 + quad * 8);
        #pragma unroll
        for (int nj = 0; nj < 4; ++nj)
            bf[nj] = *(const short8*)(b_s + (64 * h + 16 * nj + l15) * 136 + kt * 32 + quad * 8);
        #pragma unroll
        for (int mi = 0; mi < 2; ++mi)
            #pragma unroll
            for (int nj = 0; nj < 4; ++nj)
                acc[mi][nj] = __builtin_amdgcn_mfma_f32_16x16x32_bf16(af[mi], bf[nj], acc[mi][nj], 0, 0, 0);
    }
    __syncthreads();   // tiles dead -> overlay C into a_s
    #pragma unroll
    for (int mi = 0; mi < 2; ++mi)
        #pragma unroll
        for (int nj = 0; nj < 4; ++nj)
            #pragma unroll
            for (int r = 0; r < 4; ++r)
                a_s[(32 * g + 16 * mi + quad * 4 + r) * 136 + 64 * h + 16 * nj + l15] = f2bf(acc[mi][nj][r]);
    __syncthreads();
    {   // coalesced store C -> qkvbuf
        int row = t >> 2, seg = t & 3;
        const ushort_t* src = a_s + row * 136 + seg * 32;
        ushort_t* dst = qkvbuf + (size_t)(m0 + row) * 384 + n0 + seg * 32;
        *(u32x4*)(dst)      = *(const u32x4*)(src);
        *(u32x4*)(dst + 8)  = *(const u32x4*)(src + 8);
        *(u32x4*)(dst + 16) = *(const u32x4*)(src + 16);
        *(u32x4*)(dst + 24) = *(const u32x4*)(src + 24);
    }
}

// ---------------- K2b: per-window attention core + proj + residual ----------------
// LDS (71680 B, 2/CU... actually 3/CU needs <=54613 — we use 54272): q 18432 (P reuse),
// k 17408 (O reuse), vT 18432.
__global__ __launch_bounds__(256, 3) void attn_fused_k(
    const ushort_t* __restrict__ qkvbuf,  // [32768][384] for this (half,branch)
    const ushort_t* __restrict__ xn,      // [65536][256] (residual source)
    const ushort_t* __restrict__ wpT, const float* __restrict__ bp,
    const float* __restrict__ table,
    ushort_t* __restrict__ bout,
    int p_base, int chOff, int br)
{
    __shared__ __align__(16) char smem_raw[54272];
    ushort_t* q_s = (ushort_t*)smem_raw;                 // q [64][136] / P [2][64][72]
    ushort_t* k_s = (ushort_t*)(smem_raw + 18432);       // k [64][136] / O [64][136]
    ushort_t* v_s = (ushort_t*)(smem_raw + 35840);       // vT [128][72]

    const int wid = blockIdx.x;
    const int t = threadIdx.x;
    const int wv = t >> 6, lane = t & 63, l15 = lane & 15, quad = lane >> 4;

    const int WwLog = br ? 4 : 2;
    const int WhLog = br ? 2 : 4;
    const int nWxLog = 8 - WwLog;
    const int wx = wid & ((1 << nWxLog) - 1);
    const int wy = wid >> nWxLog;
    const int WwM1 = (1 << WwLog) - 1, WhM1 = (1 << WhLog) - 1;
    const int biasMul = 2 * (1 << WwLog) - 1;

    auto tokLocal = [&](int n) -> int {   // local (within half) pixel index
        int i = n >> WwLog, j = n & WwM1;
        return ((wy << WhLog) + i) * 256 + (wx << WwLog) + j;
    };

    // phase 0: load q,k (row tiles) and v (transposed) from qkvbuf
    {
        int tok = t >> 2, seg = t & 3;
        int tl = tokLocal(tok);
        const ushort_t* qsrc = qkvbuf + (size_t)tl * 384 + seg * 32;
        ushort_t* qd = q_s + tok * 136 + seg * 32;
        *(u32x4*)(qd)      = *(const u32x4*)(qsrc);
        *(u32x4*)(qd + 8)  = *(const u32x4*)(qsrc + 8);
        *(u32x4*)(qd + 16) = *(const u32x4*)(qsrc + 16);
        *(u32x4*)(qd + 24) = *(const u32x4*)(qsrc + 24);
        const ushort_t* ksrc = qsrc + 128;
        ushort_t* kd = k_s + tok * 136 + seg * 32;
        *(u32x4*)(kd)      = *(const u32x4*)(ksrc);
        *(u32x4*)(kd + 8)  = *(const u32x4*)(ksrc + 8);
        *(u32x4*)(kd + 16) = *(const u32x4*)(ksrc + 16);
        *(u32x4*)(kd + 24) = *(const u32x4*)(ksrc + 24);
        alignas(16) ushort_t vr[32];
        const ushort_t* vsrc = qsrc + 256;
        *(u32x4*)(vr)      = *(const u32x4*)(vsrc);
        *(u32x4*)(vr + 8)  = *(const u32x4*)(vsrc + 8);
        *(u32x4*)(vr + 16) = *(const u32x4*)(vsrc + 16);
        *(u32x4*)(vr + 24) = *(const u32x4*)(vsrc + 24);
        #pragma unroll
        for (int k = 0; k < 32; ++k) v_s[(seg * 32 + k) * 72 + tok] = vr[k];
    }
    __syncthreads();

    // phase 1: S = scale*QK^T + bias, softmax in registers
    float pvals[2][4][4];
    #pragma unroll
    for (int head = 0; head < 2; ++head) {
        floatx4 sacc[4];
        #pragma unroll
        for (int nt = 0; nt < 4; ++nt) sacc[nt] = floatx4{0.f, 0.f, 0.f, 0.f};
        #pragma unroll
        for (int kt = 0; kt < 2; ++kt) {
            short8 aq = *(const short8*)(q_s + (16 * wv + l15) * 136 + head * 64 + kt * 32 + quad * 8);
            #pragma unroll
            for (int nt = 0; nt < 4; ++nt) {
                short8 bk = *(const short8*)(k_s + (nt * 16 + l15) * 136 + head * 64 + kt * 32 + quad * 8);
                sacc[nt] = __builtin_amdgcn_mfma_f32_16x16x32_bf16(aq, bk, sacc[nt], 0, 0, 0);
            }
        }
        #pragma unroll
        for (int r = 0; r < 4; ++r) {
            int qrow = 16 * wv + quad * 4 + r;
            int iq = qrow >> WwLog, jq = qrow & WwM1;
            float v[4], mx = -1e30f;
            #pragma unroll
            for (int nt = 0; nt < 4; ++nt) {
                int kcol = nt * 16 + l15;
                int ik = kcol >> WwLog, jk = kcol & WwM1;
                int idx = (iq - ik + WhM1) * biasMul + (jq - jk + WwM1);
                v[nt] = sacc[nt][r] * 0.125f + table[idx * 2 + head];
                mx = fmaxf(mx, v[nt]);
            }
            mx = fmaxf(mx, __shfl_xor(mx, 1)); mx = fmaxf(mx, __shfl_xor(mx, 2));
            mx = fmaxf(mx, __shfl_xor(mx, 4)); mx = fmaxf(mx, __shfl_xor(mx, 8));
            float e[4], sm = 0.f;
            #pragma unroll
            for (int nt = 0; nt < 4; ++nt) { e[nt] = __expf(v[nt] - mx); sm += e[nt]; }
            sm += __shfl_xor(sm, 1); sm += __shfl_xor(sm, 2);
            sm += __shfl_xor(sm, 4); sm += __shfl_xor(sm, 8);
            float inv = 1.f / sm;
            #pragma unroll
            for (int nt = 0; nt < 4; ++nt) pvals[head][nt][r] = e[nt] * inv;
        }
    }
    __syncthreads();   // q_s/k_s reads complete

    {   // P (bf16) -> q_s region [2][64][72]
        ushort_t* p_s = q_s;
        #pragma unroll
        for (int head = 0; head < 2; ++head)
            #pragma unroll
            for (int nt = 0; nt < 4; ++nt)
                #pragma unroll
                for (int r = 0; r < 4; ++r) {
                    int row = 16 * wv + quad * 4 + r;
                    p_s[(head * 64 + row) * 72 + nt * 16 + l15] = f2bf(pvals[head][nt][r]);
                }
    }
    LDS_ROUNDTRIP_FENCE();
    // phase 2: O = P @ V -> k_s region [64][136]
    {
        const ushort_t* p_s = q_s;
        ushort_t* o_s = k_s;
        #pragma unroll
        for (int head = 0; head < 2; ++head) {
            short8 ap[2];
            #pragma unroll
            for (int kt = 0; kt < 2; ++kt)
                ap[kt] = *(const short8*)(p_s + (head * 64 + 16 * wv + l15) * 72 + kt * 32 + quad * 8);
            #pragma unroll
            for (int nt = 0; nt < 4; ++nt) {
                floatx4 acc = {0.f, 0.f, 0.f, 0.f};
                #pragma unroll
                for (int kt = 0; kt < 2; ++kt) {
                    short8 bv = *(const short8*)(v_s + (head * 64 + nt * 16 + l15) * 72 + kt * 32 + quad * 8);
                    acc = __builtin_amdgcn_mfma_f32_16x16x32_bf16(ap[kt], bv, acc, 0, 0, 0);
                }
                #pragma unroll
                for (int r = 0; r < 4; ++r)
                    o_s[(16 * wv + quad * 4 + r) * 136 + head * 64 + nt * 16 + l15] = f2bf(acc[r]);
            }
        }
    }
    __syncthreads();

    // phase 3: proj + bias + residual (xn direct from global) -> bout
    {
        const ushort_t* o_s = k_s;
        short8 ao[4];
        #pragma unroll
        for (int kt = 0; kt < 4; ++kt)
            ao[kt] = *(const short8*)(o_s + (16 * wv + l15) * 136 + kt * 32 + quad * 8);
        #pragma unroll
        for (int nt = 0; nt < 8; ++nt) {
            floatx4 acc = {0.f, 0.f, 0.f, 0.f};
            const ushort_t* wb = wpT + (size_t)(nt * 16 + l15) * 128 + quad * 8;
            #pragma unroll
            for (int kt = 0; kt < 4; ++kt)
                acc = __builtin_amdgcn_mfma_f32_16x16x32_bf16(ao[kt],
                        *(const short8*)(wb + kt * 32), acc, 0, 0, 0);
            int col = nt * 16 + l15;
            float bpv = bp[col];
            #pragma unroll
            for (int r = 0; r < 4; ++r) {
                int row = 16 * wv + quad * 4 + r;
                size_t gaddr = (size_t)(p_base + tokLocal(row)) * 256 + chOff + col;
                float res = acc[r] + bpv + bf2f(xn[gaddr]);
                bout[gaddr] = f2bf(res);
            }
        }
    }
}

// ---------------- K3 v3: fused MLP, dual weight buffers (unchanged from R5) ----------------
__global__ __launch_bounds__(512, 2) void mlp_k(
    const float* __restrict__ x,          // NCHW fp32
    const ushort_t* __restrict__ bout,    // NHWC bf16
    const float* __restrict__ g2, const float* __restrict__ b2,
    const ushort_t* __restrict__ w1p, const float* __restrict__ b1,
    const ushort_t* __restrict__ w2p, const float* __restrict__ bm2,
    float* __restrict__ out)
{
    __shared__ __align__(16) char smem_raw[156672];
    ushort_t* x2_s  = (ushort_t*)smem_raw;                 // [128][264]
    ushort_t* wbufA = (ushort_t*)(smem_raw + 67584);       // [64][264]  w1 chunk
    ushort_t* wbufB = (ushort_t*)(smem_raw + 101376);      // [256][72]  w2 chunk
    ushort_t* hbuf  = (ushort_t*)(smem_raw + 138240);      // [128][72]
    ushort_t* xn_s  = (ushort_t*)(smem_raw + 67584);       // overlay, transient
    ushort_t* ot_s  = (ushort_t*)smem_raw;                 // overlay [256][136]

    const int t = threadIdx.x;
    const int p0 = blockIdx.x * 128;
    const int wv = t >> 6, lane = t & 63, l15 = lane & 15, quad = lane >> 4;

    {
        const int pg = t & 31;
        const int cb = t >> 5;
        for (int it = 0; it < 16; ++it) {
            int c = cb + 16 * it;
            floatx4 v = *(const floatx4*)(x + (size_t)c * 65536 + p0 + pg * 4);
            #pragma unroll
            for (int k = 0; k < 4; ++k) x2_s[(pg * 4 + k) * 264 + c] = f2bf(v[k]);
        }
    }
    __syncthreads();
    {
        const int row = t >> 2, part = t & 3;
        float vals[64];
        float s = 0.f, ss = 0.f;
        const ushort_t* bpr = bout + (size_t)(p0 + row) * 256 + part * 64;
        ushort_t* xpr = x2_s + row * 264 + part * 64;
        #pragma unroll
        for (int k8 = 0; k8 < 8; ++k8) {
            u32x4 bv = *(const u32x4*)(bpr + k8 * 8);
            u32x4 xv = *(const u32x4*)(xpr + k8 * 8);
            const ushort_t* pb = (const ushort_t*)&bv;
            const ushort_t* px = (const ushort_t*)&xv;
            #pragma unroll
            for (int k = 0; k < 8; ++k) {
                float v = bf2f(px[k]) + bf2f(pb[k]);
                vals[k8 * 8 + k] = v; s += v; ss += v * v;
            }
        }
        s  += __shfl_xor(s, 1);  s  += __shfl_xor(s, 2);
        ss += __shfl_xor(ss, 1); ss += __shfl_xor(ss, 2);
        float mean = s * (1.f / 256.f);
        float rstd = rsqrtf(ss * (1.f / 256.f) - mean * mean + 1e-5f);
        const float* g2p = g2 + part * 64;
        const float* b2p = b2 + part * 64;
        ushort_t* npr = xn_s + row * 264 + part * 64;
        #pragma unroll
        for (int k8 = 0; k8 < 8; ++k8) {
            alignas(16) ushort_t o8[8], n8[8];
            #pragma unroll
            for (int k = 0; k < 8; ++k) {
                float v = vals[k8 * 8 + k];
                o8[k] = f2bf(v);
                n8[k] = f2bf((v - mean) * rstd * g2p[k8 * 8 + k] + b2p[k8 * 8 + k]);
            }
            *(u32x4*)(xpr + k8 * 8) = *(const u32x4*)o8;
            *(u32x4*)(npr + k8 * 8) = *(const u32x4*)n8;
        }
    }
    __syncthreads();

    const int g1g = wv & 3, g1h = wv >> 2;
    const int g2a = wv & 1, g2qd = wv >> 1;

    short8 afrag[2][8];
    #pragma unroll
    for (int mi = 0; mi < 2; ++mi)
        #pragma unroll
        for (int kt = 0; kt < 8; ++kt)
            afrag[mi][kt] = *(const short8*)(xn_s + (32 * g1g + 16 * mi + l15) * 264 + kt * 32 + quad * 8);

    u32x4* bufA16 = (u32x4*)wbufA;
    u32x4* bufB16 = (u32x4*)wbufB;
    u32x4 w1reg[5], w2reg[5];
    {
        const u32x4* s1 = (const u32x4*)w1p;
        #pragma unroll
        for (int j = 0; j < 4; ++j) w1reg[j] = s1[j * 512 + t];
        if (t < 64) w1reg[4] = s1[2048 + t];
        const u32x4* s2 = (const u32x4*)w2p;
        #pragma unroll
        for (int j = 0; j < 4; ++j) w2reg[j] = s2[j * 512 + t];
        if (t < 256) w2reg[4] = s2[2048 + t];
    }
    __syncthreads();
    {
        #pragma unroll
        for (int j = 0; j < 4; ++j) bufA16[j * 512 + t] = w1reg[j];
        if (t < 64) bufA16[2048 + t] = w1reg[4];
        #pragma unroll
        for (int j = 0; j < 4; ++j) bufB16[j * 512 + t] = w2reg[j];
        if (t < 256) bufB16[2048 + t] = w2reg[4];
        const u32x4* s1 = (const u32x4*)(w1p + 16896);
        #pragma unroll
        for (int j = 0; j < 4; ++j) w1reg[j] = s1[j * 512 + t];
        if (t < 64) w1reg[4] = s1[2048 + t];
    }
    __syncthreads();

    floatx4 oacc[4][4];
    #pragma unroll
    for (int mi = 0; mi < 4; ++mi)
        #pragma unroll
        for (int nj = 0; nj < 4; ++nj) oacc[mi][nj] = floatx4{0.f, 0.f, 0.f, 0.f};

    for (int ch = 0; ch < 16; ++ch) {
        floatx4 hacc[2][2];
        #pragma unroll
        for (int mi = 0; mi < 2; ++mi)
            #pragma unroll
            for (int nj = 0; nj < 2; ++nj) hacc[mi][nj] = floatx4{0.f, 0.f, 0.f, 0.f};
        #pragma unroll
        for (int nj = 0; nj < 2; ++nj) {
            #pragma unroll
            for (int kt = 0; kt < 8; ++kt) {
                short8 bfr = *(const short8*)(wbufA + (32 * g1h + 16 * nj + l15) * 264 + kt * 32 + quad * 8);
                #pragma unroll
                for (int mi = 0; mi < 2; ++mi)
                    hacc[mi][nj] = __builtin_amdgcn_mfma_f32_16x16x32_bf16(afrag[mi][kt], bfr, hacc[mi][nj], 0, 0, 0);
            }
        }
        #pragma unroll
        for (int nj = 0; nj < 2; ++nj) {
            int col = 32 * g1h + 16 * nj + l15;
            float bb = b1[ch * 64 + col];
            #pragma unroll
            for (int mi = 0; mi < 2; ++mi)
                #pragma unroll
                for (int r = 0; r < 4; ++r) {
                    float v = gelu_f(hacc[mi][nj][r] + bb);
                    hbuf[(32 * g1g + 16 * mi + quad * 4 + r) * 72 + col] = f2bf(v);
                }
        }
        if (ch < 15) {
            const u32x4* s2 = (const u32x4*)(w2p + (ch + 1) * 18432);
            #pragma unroll
            for (int j = 0; j < 4; ++j) w2reg[j] = s2[j * 512 + t];
            if (t < 256) w2reg[4] = s2[2048 + t];
        }
        __syncthreads();
        if (ch < 15) {
            #pragma unroll
            for (int j = 0; j < 4; ++j) bufA16[j * 512 + t] = w1reg[j];
            if (t < 64) bufA16[2048 + t] = w1reg[4];
        }
        #pragma unroll
        for (int kt = 0; kt < 2; ++kt) {
            short8 hfrag[4];
            #pragma unroll
            for (int mi = 0; mi < 4; ++mi)
                hfrag[mi] = *(const short8*)(hbuf + (64 * g2a + 16 * mi + l15) * 72 + kt * 32 + quad * 8);
            #pragma unroll
            for (int nj = 0; nj < 4; ++nj) {
                short8 bfr = *(const short8*)(wbufB + (64 * g2qd + 16 * nj + l15) * 72 + kt * 32 + quad * 8);
                #pragma unroll
                for (int mi = 0; mi < 4; ++mi)
                    oacc[mi][nj] = __builtin_amdgcn_mfma_f32_16x16x32_bf16(hfrag[mi], bfr, oacc[mi][nj], 0, 0, 0);
            }
        }
        if (ch < 14) {
            const u32x4* s1 = (const u32x4*)(w1p + (ch + 2) * 16896);
            #pragma unroll
            for (int j = 0; j < 4; ++j) w1reg[j] = s1[j * 512 + t];
            if (t < 64) w1reg[4] = s1[2048 + t];
        }
        __syncthreads();
        if (ch < 15) {
            #pragma unroll
            for (int j = 0; j < 4; ++j) bufB16[j * 512 + t] = w2reg[j];
            if (t < 256) bufB16[2048 + t] = w2reg[4];
        }
    }

    #pragma unroll
    for (int nj = 0; nj < 4; ++nj) {
        int col = 64 * g2qd + 16 * nj + l15;
        float bb = bm2[col];
        #pragma unroll
        for (int mi = 0; mi < 4; ++mi)
            #pragma unroll
            for (int r = 0; r < 4; ++r) {
                int row = 64 * g2a + 16 * mi + quad * 4 + r;
                oacc[mi][nj][r] += bb + bf2f(x2_s[row * 264 + col]);
            }
    }
    __syncthreads();
    #pragma unroll
    for (int nj = 0; nj < 4; ++nj) {
        int col = 64 * g2qd + 16 * nj + l15;
        #pragma unroll
        for (int mi = 0; mi < 4; ++mi)
            #pragma unroll
            for (int r = 0; r < 4; ++r)
                ot_s[col * 136 + 64 * g2a + 16 * mi + quad * 4 + r] = f2bf(oacc[mi][nj][r]);
    }
    __syncthreads();
    {
        int c = t >> 1, half = t & 1;
        #pragma unroll
        for (int j = 0; j < 16; ++j) {
            floatx4 o;
            #pragma unroll
            for (int k = 0; k < 4; ++k) o[k] = bf2f(ot_s[c * 136 + 64 * half + j * 4 + k]);
            *(floatx4*)(out + (size_t)c * 65536 + p0 + 64 * half + j * 4) = o;
        }
    }
}

extern "C" void kernel_launch(void* const* d_in, const int* in_sizes, int n_in,
                              void* d_out, int out_size, void* d_ws, size_t ws_size,
                              hipStream_t stream) {
    (void)in_sizes; (void)n_in; (void)out_size; (void)ws_size;
    const float* x     = (const float*)d_in[0];
    const float* n1g   = (const float*)d_in[1];
    const float* n1b   = (const float*)d_in[2];
    const float* qkv_r = (const float*)d_in[3];
    const float* pr_w  = (const float*)d_in[4];
    const float* pr_b  = (const float*)d_in[5];
    const float* tab_r = (const float*)d_in[6];
    const float* qkv_a = (const float*)d_in[7];
    const float* pa_w  = (const float*)d_in[8];
    const float* pa_b  = (const float*)d_in[9];
    const float* tab_a = (const float*)d_in[10];
    const float* n2g   = (const float*)d_in[11];
    const float* n2b   = (const float*)d_in[12];
    const float* w1    = (const float*)d_in[13];
    const float* b1    = (const float*)d_in[14];
    const float* w2    = (const float*)d_in[15];
    const float* b2    = (const float*)d_in[16];

    char* ws = (char*)d_ws;
    ushort_t* wqkvT_r = (ushort_t*)(ws);              //  98304 B
    ushort_t* wqkvT_a = (ushort_t*)(ws + 98304);      //  98304 B
    ushort_t* wpT_r   = (ushort_t*)(ws + 196608);     //  32768 B
    ushort_t* wpT_a   = (ushort_t*)(ws + 229376);     //  32768 B
    ushort_t* w1p     = (ushort_t*)(ws + 262144);     // 540672 B
    ushort_t* w2p     = (ushort_t*)(ws + 802816);     // 589824 B
    ushort_t* bout    = (ushort_t*)(ws + 1392640);    // 33554432 B
    // d_out (64 MiB): lower 32 MiB = xn (bf16); upper 32 MiB = qkv scratch (24 MiB used).
    ushort_t* xn      = (ushort_t*)d_out;
    ushort_t* qkvbuf  = (ushort_t*)d_out + 16777216;  // byte offset 32 MiB

    transpose_k<<<dim3(24, 8), 256, 0, stream>>>(qkv_r, wqkvT_r, 128, 384);
    transpose_k<<<dim3(24, 8), 256, 0, stream>>>(qkv_a, wqkvT_a, 128, 384);
    transpose_k<<<dim3(8, 8),  256, 0, stream>>>(pr_w, wpT_r, 128, 128);
    transpose_k<<<dim3(8, 8),  256, 0, stream>>>(pa_w, wpT_a, 128, 128);
    w1prep_k<<<dim3(16, 4), 256, 0, stream>>>(w1, w1p);
    w2prep_k<<<dim3(16, 4), 256, 0, stream>>>(w2, w2p);
    ln1_k<<<1024, 256, 0, stream>>>(x, n1g, n1b, xn);

    for (int half = 0; half < 2; ++half) {
        int p_base = half * 32768;
        for (int br = 0; br < 2; ++br) {
            const ushort_t* wq = br ? wqkvT_a : wqkvT_r;
            const ushort_t* wp = br ? wpT_a : wpT_r;
            const float* bpv   = br ? pa_b : pr_b;
            const float* tab   = br ? tab_a : tab_r;
            qkv_half_k<<<dim3(256, 3), 512, 0, stream>>>(xn, wq, qkvbuf, p_base, br * 128);
            attn_fused_k<<<512, 256, 0, stream>>>(qkvbuf, xn, wp, bpv, tab, bout,
                                                  p_base, br * 128, br);
        }
    }
    mlp_k<<<512, 512, 0, stream>>>(x, bout, n2g, n2b, w1p, b1, w2p, b2, (float*)d_out);
}

// Round 7
// 427.674 us; speedup vs baseline: 1.0973x; 1.0973x over previous
//
#include <hip/hip_runtime.h>
#include <stdint.h>

typedef unsigned short ushort_t;
typedef __attribute__((ext_vector_type(8))) short short8;       // 8 x bf16 (MFMA A/B frag)
typedef __attribute__((ext_vector_type(4))) float floatx4;      // 16x16 C frag / 16B fp32
typedef __attribute__((ext_vector_type(16))) float floatx16;    // 32x32 C frag
typedef __attribute__((ext_vector_type(4))) unsigned int u32x4; // 16B vector

__device__ __forceinline__ float bf2f(ushort_t u) {
    union { unsigned int i; float f; } v; v.i = ((unsigned int)u) << 16; return v.f;
}
__device__ __forceinline__ ushort_t f2bf(float f) {
    union { float ff; unsigned int i; } v; v.ff = f;
    unsigned int x = v.i;
    return (ushort_t)((x + 0x7fffu + ((x >> 16) & 1u)) >> 16);  // RNE
}
__device__ __forceinline__ float gelu_f(float v) {
    float u = v * (0.7978845608f + 0.0356774081f * v * v);
    float e = __expf(2.f * u);
    float th = 1.f - 2.f / (e + 1.f);    // tanh(u)
    return 0.5f * v * (1.f + th);
}
#define LDS_ROUNDTRIP_FENCE() __asm__ volatile("s_waitcnt lgkmcnt(0)" ::: "memory")

// ================= prep_k: ln1 (blocks 0..1023) + all weight preps (1024..1663) ==========
__global__ __launch_bounds__(256) void prep_k(
    const float* __restrict__ x, const float* __restrict__ n1g, const float* __restrict__ n1b,
    ushort_t* __restrict__ xn,
    const float* __restrict__ qkv_r, ushort_t* __restrict__ wqkvT_r,
    const float* __restrict__ qkv_a, ushort_t* __restrict__ wqkvT_a,
    const float* __restrict__ pr_w,  ushort_t* __restrict__ wpT_r,
    const float* __restrict__ pa_w,  ushort_t* __restrict__ wpT_a,
    const float* __restrict__ w1,    ushort_t* __restrict__ w1p,
    const float* __restrict__ w2,    ushort_t* __restrict__ w2p)
{
    __shared__ __align__(16) char pshm[33792];
    const int t = threadIdx.x;
    int b = blockIdx.x;
    if (b < 1024) {
        // ---- LN1 + NCHW(fp32) -> NHWC(bf16) ----
        ushort_t* tile = (ushort_t*)pshm;    // [64][264]
        const int p0 = b * 64;
        {
            const int pg = t & 15, cb = t >> 4;
            for (int it = 0; it < 16; ++it) {
                int c = cb + 16 * it;
                floatx4 v = *(const floatx4*)(x + (size_t)c * 65536 + p0 + pg * 4);
                #pragma unroll
                for (int k = 0; k < 4; ++k) tile[(pg * 4 + k) * 264 + c] = f2bf(v[k]);
            }
        }
        __syncthreads();
        const int pix = t >> 2, part = t & 3;
        float vals[64];
        float s = 0.f, ss = 0.f;
        #pragma unroll
        for (int k = 0; k < 64; ++k) {
            float v = bf2f(tile[pix * 264 + part * 64 + k]);
            vals[k] = v; s += v; ss += v * v;
        }
        s  += __shfl_xor(s, 1);  s  += __shfl_xor(s, 2);
        ss += __shfl_xor(ss, 1); ss += __shfl_xor(ss, 2);
        float mean = s * (1.f / 256.f);
        float rstd = rsqrtf(ss * (1.f / 256.f) - mean * mean + 1e-5f);
        size_t obase = (size_t)(p0 + pix) * 256 + part * 64;
        #pragma unroll
        for (int k8 = 0; k8 < 8; ++k8) {
            alignas(16) ushort_t o8[8];
            #pragma unroll
            for (int k = 0; k < 8; ++k) {
                int c = part * 64 + k8 * 8 + k;
                o8[k] = f2bf((vals[k8 * 8 + k] - mean) * rstd * n1g[c] + n1b[c]);
            }
            *(u32x4*)(xn + obase + k8 * 8) = *(const u32x4*)o8;
        }
        return;
    }
    b -= 1024;
    if (b < 512) {
        // ---- simple transposes fp32 [R][C] -> bf16 [C][R] ----
        const float* src; ushort_t* dst; int R, C, bi;
        if (b < 192)      { src = qkv_r; dst = wqkvT_r; R = 128; C = 384; bi = b;       }
        else if (b < 384) { src = qkv_a; dst = wqkvT_a; R = 128; C = 384; bi = b - 192; }
        else if (b < 448) { src = pr_w;  dst = wpT_r;   R = 128; C = 128; bi = b - 384; }
        else              { src = pa_w;  dst = wpT_a;   R = 128; C = 128; bi = b - 448; }
        int nbx = C / 16;
        int c0 = (bi % nbx) * 16, r0 = (bi / nbx) * 16;
        float* ts = (float*)pshm;    // [16][17]
        int tx = t & 15, ty = t >> 4;
        ts[ty * 17 + tx] = src[(size_t)(r0 + ty) * C + (c0 + tx)];
        __syncthreads();
        dst[(size_t)(c0 + ty) * R + (r0 + tx)] = f2bf(ts[tx * 17 + ty]);
        return;
    }
    b -= 512;
    float* s = (float*)pshm;   // [64][65]
    if (b < 64) {
        // ---- w1prep: w1 fp32 [256][1024] -> [16][64][264] ----
        const int ch = b & 15, k0 = (b >> 4) * 64;
        {
            int nn = t & 63, kr = t >> 6;
            for (int j = 0; j < 16; ++j) {
                int kk = j * 4 + kr;
                s[kk * 65 + nn] = w1[(size_t)(k0 + kk) * 1024 + ch * 64 + nn];
            }
        }
        __syncthreads();
        {
            int kk = t & 63, nr = t >> 6;
            for (int j = 0; j < 16; ++j) {
                int n2 = j * 4 + nr;
                w1p[(size_t)ch * 16896 + n2 * 264 + k0 + kk] = f2bf(s[kk * 65 + n2]);
            }
        }
        return;
    }
    b -= 64;
    {
        // ---- w2prep: w2 fp32 [1024][256] -> [16][256][72] ----
        const int ch = b & 15, n0 = (b >> 4) * 64;
        {
            int nn = t & 63, kr = t >> 6;
            for (int j = 0; j < 16; ++j) {
                int kk = j * 4 + kr;
                s[kk * 65 + nn] = w2[(size_t)(ch * 64 + kk) * 256 + n0 + nn];
            }
        }
        __syncthreads();
        {
            int kk = t & 63, nr = t >> 6;
            for (int j = 0; j < 16; ++j) {
                int n2 = j * 4 + nr;
                w2p[(size_t)ch * 18432 + (n0 + n2) * 72 + kk] = f2bf(s[kk * 65 + n2]);
            }
        }
    }
}

// ================= attn_k: one window per block (R5 monolithic, reverted) =================
__global__ __launch_bounds__(256, 2) void attn_k(
    const ushort_t* __restrict__ xn,
    const ushort_t* __restrict__ wqkvT_r, const ushort_t* __restrict__ wpT_r,
    const float* __restrict__ bp_r, const float* __restrict__ table_r,
    const ushort_t* __restrict__ wqkvT_a, const ushort_t* __restrict__ wpT_a,
    const float* __restrict__ bp_a, const float* __restrict__ table_a,
    ushort_t* __restrict__ bout)
{
    __shared__ __align__(16) char smem_raw[71680];
    ushort_t* xw_s = (ushort_t*)smem_raw;                   // [64][136]
    ushort_t* q_s  = (ushort_t*)(smem_raw + 17408);         // q [64][136] / P [2][64][72]
    ushort_t* k_s  = (ushort_t*)(smem_raw + 35840);         // k [64][136] / O [64][136]
    ushort_t* v_s  = (ushort_t*)(smem_raw + 53248);         // vT [128][72]

    const int br  = blockIdx.y;
    const int wid = blockIdx.x;
    const int t = threadIdx.x;
    const int wv = t >> 6, lane = t & 63, l15 = lane & 15, quad = lane >> 4;

    const int WwLog = br ? 4 : 2;
    const int WhLog = br ? 2 : 4;
    const int nWxLog = 8 - WwLog;
    const int wx = wid & ((1 << nWxLog) - 1);
    const int wy = wid >> nWxLog;
    const int chOff = br ? 128 : 0;
    const int WwM1 = (1 << WwLog) - 1, WhM1 = (1 << WhLog) - 1;
    const int biasMul = 2 * (1 << WwLog) - 1;
    const ushort_t* wqkvT = br ? wqkvT_a : wqkvT_r;
    const ushort_t* wpT   = br ? wpT_a   : wpT_r;
    const float* bp    = br ? bp_a    : bp_r;
    const float* table = br ? table_a : table_r;

    auto tok2p = [&](int n) -> int {
        int i = n >> WwLog, j = n & WwM1;
        return ((wy << WhLog) + i) * 256 + (wx << WwLog) + j;
    };

    {
        int tok = t >> 2, seg = t & 3;
        const ushort_t* src = xn + (size_t)tok2p(tok) * 256 + chOff + seg * 32;
        ushort_t* dst = xw_s + tok * 136 + seg * 32;
        *(u32x4*)(dst)      = *(const u32x4*)(src);
        *(u32x4*)(dst + 8)  = *(const u32x4*)(src + 8);
        *(u32x4*)(dst + 16) = *(const u32x4*)(src + 16);
        *(u32x4*)(dst + 24) = *(const u32x4*)(src + 24);
    }
    __syncthreads();

    {
        short8 afrag[4];
        #pragma unroll
        for (int kt = 0; kt < 4; ++kt)
            afrag[kt] = *(const short8*)(xw_s + (16 * wv + l15) * 136 + kt * 32 + quad * 8);
        for (int nt = 0; nt < 24; ++nt) {
            floatx4 acc = {0.f, 0.f, 0.f, 0.f};
            const ushort_t* wb = wqkvT + (size_t)(nt * 16 + l15) * 128 + quad * 8;
            #pragma unroll
            for (int kt = 0; kt < 4; ++kt)
                acc = __builtin_amdgcn_mfma_f32_16x16x32_bf16(afrag[kt],
                        *(const short8*)(wb + kt * 32), acc, 0, 0, 0);
            int ncol = nt * 16 + l15;
            #pragma unroll
            for (int r = 0; r < 4; ++r) {
                int row = 16 * wv + quad * 4 + r;
                ushort_t val = f2bf(acc[r]);
                if (ncol < 128)      q_s[row * 136 + ncol] = val;
                else if (ncol < 256) k_s[row * 136 + (ncol - 128)] = val;
                else                 v_s[(ncol - 256) * 72 + row] = val;
            }
        }
    }
    __syncthreads();

    float pvals[2][4][4];
    #pragma unroll
    for (int head = 0; head < 2; ++head) {
        floatx4 sacc[4];
        #pragma unroll
        for (int nt = 0; nt < 4; ++nt) sacc[nt] = floatx4{0.f, 0.f, 0.f, 0.f};
        #pragma unroll
        for (int kt = 0; kt < 2; ++kt) {
            short8 aq = *(const short8*)(q_s + (16 * wv + l15) * 136 + head * 64 + kt * 32 + quad * 8);
            #pragma unroll
            for (int nt = 0; nt < 4; ++nt) {
                short8 bk = *(const short8*)(k_s + (nt * 16 + l15) * 136 + head * 64 + kt * 32 + quad * 8);
                sacc[nt] = __builtin_amdgcn_mfma_f32_16x16x32_bf16(aq, bk, sacc[nt], 0, 0, 0);
            }
        }
        #pragma unroll
        for (int r = 0; r < 4; ++r) {
            int qrow = 16 * wv + quad * 4 + r;
            int iq = qrow >> WwLog, jq = qrow & WwM1;
            float v[4], mx = -1e30f;
            #pragma unroll
            for (int nt = 0; nt < 4; ++nt) {
                int kcol = nt * 16 + l15;
                int ik = kcol >> WwLog, jk = kcol & WwM1;
                int idx = (iq - ik + WhM1) * biasMul + (jq - jk + WwM1);
                v[nt] = sacc[nt][r] * 0.125f + table[idx * 2 + head];
                mx = fmaxf(mx, v[nt]);
            }
            mx = fmaxf(mx, __shfl_xor(mx, 1)); mx = fmaxf(mx, __shfl_xor(mx, 2));
            mx = fmaxf(mx, __shfl_xor(mx, 4)); mx = fmaxf(mx, __shfl_xor(mx, 8));
            float e[4], sm = 0.f;
            #pragma unroll
            for (int nt = 0; nt < 4; ++nt) { e[nt] = __expf(v[nt] - mx); sm += e[nt]; }
            sm += __shfl_xor(sm, 1); sm += __shfl_xor(sm, 2);
            sm += __shfl_xor(sm, 4); sm += __shfl_xor(sm, 8);
            float inv = 1.f / sm;
            #pragma unroll
            for (int nt = 0; nt < 4; ++nt) pvals[head][nt][r] = e[nt] * inv;
        }
    }
    __syncthreads();

    {
        ushort_t* p_s = q_s;
        #pragma unroll
        for (int head = 0; head < 2; ++head)
            #pragma unroll
            for (int nt = 0; nt < 4; ++nt)
                #pragma unroll
                for (int r = 0; r < 4; ++r) {
                    int row = 16 * wv + quad * 4 + r;
                    p_s[(head * 64 + row) * 72 + nt * 16 + l15] = f2bf(pvals[head][nt][r]);
                }
    }
    LDS_ROUNDTRIP_FENCE();
    {
        const ushort_t* p_s = q_s;
        ushort_t* o_s = k_s;
        #pragma unroll
        for (int head = 0; head < 2; ++head) {
            short8 ap[2];
            #pragma unroll
            for (int kt = 0; kt < 2; ++kt)
                ap[kt] = *(const short8*)(p_s + (head * 64 + 16 * wv + l15) * 72 + kt * 32 + quad * 8);
            #pragma unroll
            for (int nt = 0; nt < 4; ++nt) {
                floatx4 acc = {0.f, 0.f, 0.f, 0.f};
                #pragma unroll
                for (int kt = 0; kt < 2; ++kt) {
                    short8 bv = *(const short8*)(v_s + (head * 64 + nt * 16 + l15) * 72 + kt * 32 + quad * 8);
                    acc = __builtin_amdgcn_mfma_f32_16x16x32_bf16(ap[kt], bv, acc, 0, 0, 0);
                }
                #pragma unroll
                for (int r = 0; r < 4; ++r)
                    o_s[(16 * wv + quad * 4 + r) * 136 + head * 64 + nt * 16 + l15] = f2bf(acc[r]);
            }
        }
    }
    __syncthreads();

    {
        const ushort_t* o_s = k_s;
        short8 ao[4];
        #pragma unroll
        for (int kt = 0; kt < 4; ++kt)
            ao[kt] = *(const short8*)(o_s + (16 * wv + l15) * 136 + kt * 32 + quad * 8);
        #pragma unroll
        for (int nt = 0; nt < 8; ++nt) {
            floatx4 acc = {0.f, 0.f, 0.f, 0.f};
            const ushort_t* wb = wpT + (size_t)(nt * 16 + l15) * 128 + quad * 8;
            #pragma unroll
            for (int kt = 0; kt < 4; ++kt)
                acc = __builtin_amdgcn_mfma_f32_16x16x32_bf16(ao[kt],
                        *(const short8*)(wb + kt * 32), acc, 0, 0, 0);
            int col = nt * 16 + l15;
            float bpv = bp[col];
            #pragma unroll
            for (int r = 0; r < 4; ++r) {
                int row = 16 * wv + quad * 4 + r;
                float res = acc[r] + bpv + bf2f(xw_s[row * 136 + col]);
                bout[(size_t)tok2p(row) * 256 + chOff + col] = f2bf(res);
            }
        }
    }
}

// ================= mlp_k v4: M=64, 256 thr, 2 blocks/CU, 32x32x16 MFMA =================
// LDS 79872 B: x2_s [64][264] @0 (33792); wbuf @33792 (36864: w1 [64][264] / w2 [256][72]);
// hbuf [64][72] @70656 (9216). xn_s overlay on wbuf (transient). ot_s [256][72] overlay @0.
__global__ __launch_bounds__(256, 2) void mlp_k(
    const float* __restrict__ x,          // NCHW fp32
    const ushort_t* __restrict__ bout,    // NHWC bf16
    const float* __restrict__ g2, const float* __restrict__ b2,
    const ushort_t* __restrict__ w1p, const float* __restrict__ b1,
    const ushort_t* __restrict__ w2p, const float* __restrict__ bm2,
    float* __restrict__ out)
{
    __shared__ __align__(16) char smem_raw[79872];
    ushort_t* x2_s = (ushort_t*)smem_raw;               // [64][264]
    ushort_t* wbuf = (ushort_t*)(smem_raw + 33792);     // union w1/w2 chunk
    ushort_t* hbuf = (ushort_t*)(smem_raw + 70656);     // [64][72]
    ushort_t* xn_s = wbuf;                              // transient overlay
    ushort_t* ot_s = (ushort_t*)smem_raw;               // [256][72] epilogue overlay

    const int t = threadIdx.x;
    const int p0 = blockIdx.x * 64;
    const int wv = t >> 6, lane = t & 63, l31 = lane & 31, half = lane >> 5;

    {   // x fp32 NCHW tile -> x2_s bf16
        const int pg = t & 15, cb = t >> 4;
        for (int it = 0; it < 16; ++it) {
            int c = cb + 16 * it;
            floatx4 v = *(const floatx4*)(x + (size_t)c * 65536 + p0 + pg * 4);
            #pragma unroll
            for (int k = 0; k < 4; ++k) x2_s[(pg * 4 + k) * 264 + c] = f2bf(v[k]);
        }
    }
    __syncthreads();
    {   // x2 = x + bout; LN2 -> xn_s
        const int row = t >> 2, part = t & 3;
        float vals[64];
        float s = 0.f, ss = 0.f;
        const ushort_t* bpr = bout + (size_t)(p0 + row) * 256 + part * 64;
        ushort_t* xpr = x2_s + row * 264 + part * 64;
        #pragma unroll
        for (int k8 = 0; k8 < 8; ++k8) {
            u32x4 bv = *(const u32x4*)(bpr + k8 * 8);
            u32x4 xv = *(const u32x4*)(xpr + k8 * 8);
            const ushort_t* pb = (const ushort_t*)&bv;
            const ushort_t* px = (const ushort_t*)&xv;
            #pragma unroll
            for (int k = 0; k < 8; ++k) {
                float v = bf2f(px[k]) + bf2f(pb[k]);
                vals[k8 * 8 + k] = v; s += v; ss += v * v;
            }
        }
        s  += __shfl_xor(s, 1);  s  += __shfl_xor(s, 2);
        ss += __shfl_xor(ss, 1); ss += __shfl_xor(ss, 2);
        float mean = s * (1.f / 256.f);
        float rstd = rsqrtf(ss * (1.f / 256.f) - mean * mean + 1e-5f);
        const float* g2p = g2 + part * 64;
        const float* b2p = b2 + part * 64;
        ushort_t* npr = xn_s + row * 264 + part * 64;
        #pragma unroll
        for (int k8 = 0; k8 < 8; ++k8) {
            alignas(16) ushort_t o8[8], n8[8];
            #pragma unroll
            for (int k = 0; k < 8; ++k) {
                float v = vals[k8 * 8 + k];
                o8[k] = f2bf(v);
                n8[k] = f2bf((v - mean) * rstd * g2p[k8 * 8 + k] + b2p[k8 * 8 + k]);
            }
            *(u32x4*)(xpr + k8 * 8) = *(const u32x4*)o8;
            *(u32x4*)(npr + k8 * 8) = *(const u32x4*)n8;
        }
    }
    __syncthreads();

    // GEMM1 wave tile: rows 32*g1m..+31, hidden cols 32*g1n..+31 of the 64-col chunk
    const int g1m = wv & 1, g1n = wv >> 1;
    // GEMM2 wave tiles: rows 32*g2m..+31, out cols g2nb + {0,32,64,96}
    const int g2m = wv & 1;
    const int g2nb = 128 * (wv >> 1);

    short8 afrag[16];    // xn rows (32) x K=256, register-resident
    #pragma unroll
    for (int ks = 0; ks < 16; ++ks)
        afrag[ks] = *(const short8*)(xn_s + (32 * g1m + l31) * 264 + ks * 16 + half * 8);

    u32x4* wb16 = (u32x4*)wbuf;
    u32x4 w1reg[9], w2reg[9];
    {   // w1[0] chunk: 33792 B = 2112 u32x4 = 8*256 + 64
        const u32x4* s1 = (const u32x4*)w1p;
        #pragma unroll
        for (int j = 0; j < 8; ++j) w1reg[j] = s1[j * 256 + t];
        if (t < 64) w1reg[8] = s1[2048 + t];
    }
    __syncthreads();   // all afrag reads done (xn_s dead)
    {
        #pragma unroll
        for (int j = 0; j < 8; ++j) wb16[j * 256 + t] = w1reg[j];
        if (t < 64) wb16[2048 + t] = w1reg[8];
    }
    __syncthreads();   // wbuf = w1[0]

    floatx16 oacc[4];
    #pragma unroll
    for (int nt = 0; nt < 4; ++nt)
        #pragma unroll
        for (int i = 0; i < 16; ++i) oacc[nt][i] = 0.f;

    for (int ch = 0; ch < 16; ++ch) {
        {   // prefetch w2[ch] into regs (covered by GEMM1): 36864 B = 2304 u32x4 = 9*256
            const u32x4* s2 = (const u32x4*)(w2p + (size_t)ch * 18432);
            #pragma unroll
            for (int j = 0; j < 9; ++j) w2reg[j] = s2[j * 256 + t];
        }
        // ---- GEMM1: H-chunk = xn @ w1[ch], two interleaved accumulator chains
        floatx16 ha, hb;
        #pragma unroll
        for (int i = 0; i < 16; ++i) { ha[i] = 0.f; hb[i] = 0.f; }
        #pragma unroll
        for (int ks = 0; ks < 16; ks += 2) {
            short8 bf0 = *(const short8*)(wbuf + (32 * g1n + l31) * 264 + ks * 16 + half * 8);
            short8 bf1 = *(const short8*)(wbuf + (32 * g1n + l31) * 264 + ks * 16 + 16 + half * 8);
            ha = __builtin_amdgcn_mfma_f32_32x32x16_bf16(afrag[ks], bf0, ha, 0, 0, 0);
            hb = __builtin_amdgcn_mfma_f32_32x32x16_bf16(afrag[ks + 1], bf1, hb, 0, 0, 0);
        }
        {   // bias + GELU -> hbuf
            float bb = b1[ch * 64 + 32 * g1n + l31];
            #pragma unroll
            for (int r = 0; r < 16; ++r) {
                int row = 32 * g1m + (r & 3) + 8 * (r >> 2) + 4 * half;
                float v = gelu_f(ha[r] + hb[r] + bb);
                hbuf[row * 72 + 32 * g1n + l31] = f2bf(v);
            }
        }
        __syncthreads();                         // B1: w1 reads + hbuf writes done
        {
            #pragma unroll
            for (int j = 0; j < 9; ++j) wb16[j * 256 + t] = w2reg[j];
        }
        __syncthreads();                         // B2: wbuf = w2[ch]
        if (ch < 15) {   // prefetch w1[ch+1] (covered by GEMM2)
            const u32x4* s1 = (const u32x4*)(w1p + (size_t)(ch + 1) * 16896);
            #pragma unroll
            for (int j = 0; j < 8; ++j) w1reg[j] = s1[j * 256 + t];
            if (t < 64) w1reg[8] = s1[2048 + t];
        }
        // ---- GEMM2: out += H @ w2[ch]
        #pragma unroll
        for (int ks = 0; ks < 4; ++ks) {
            short8 haf = *(const short8*)(hbuf + (32 * g2m + l31) * 72 + ks * 16 + half * 8);
            #pragma unroll
            for (int nt = 0; nt < 4; ++nt) {
                short8 bfr = *(const short8*)(wbuf + (g2nb + 32 * nt + l31) * 72 + ks * 16 + half * 8);
                oacc[nt] = __builtin_amdgcn_mfma_f32_32x32x16_bf16(haf, bfr, oacc[nt], 0, 0, 0);
            }
        }
        __syncthreads();                         // B3: w2 + hbuf reads done
        if (ch < 15) {
            #pragma unroll
            for (int j = 0; j < 8; ++j) wb16[j * 256 + t] = w1reg[j];
            if (t < 64) wb16[2048 + t] = w1reg[8];
        }
        __syncthreads();                         // B4: wbuf = w1[ch+1]
    }

    // epilogue: + bm2 + x2 residual
    #pragma unroll
    for (int nt = 0; nt < 4; ++nt) {
        int col = g2nb + 32 * nt + l31;
        float bb = bm2[col];
        #pragma unroll
        for (int r = 0; r < 16; ++r) {
            int row = 32 * g2m + (r & 3) + 8 * (r >> 2) + 4 * half;
            oacc[nt][r] += bb + bf2f(x2_s[row * 264 + col]);
        }
    }
    __syncthreads();   // x2_s/wbuf dead -> ot_s overlay safe
    #pragma unroll
    for (int nt = 0; nt < 4; ++nt) {
        int col = g2nb + 32 * nt + l31;
        #pragma unroll
        for (int r = 0; r < 16; ++r) {
            int row = 32 * g2m + (r & 3) + 8 * (r >> 2) + 4 * half;
            ot_s[col * 72 + row] = f2bf(oacc[nt][r]);
        }
    }
    __syncthreads();
    {   // coalesced fp32 NCHW store: pixel-per-lane, channel per iteration
        for (int it = 0; it < 64; ++it) {
            int c = it * 4 + wv;
            out[(size_t)c * 65536 + p0 + lane] = bf2f(ot_s[c * 72 + lane]);
        }
    }
}

extern "C" void kernel_launch(void* const* d_in, const int* in_sizes, int n_in,
                              void* d_out, int out_size, void* d_ws, size_t ws_size,
                              hipStream_t stream) {
    (void)in_sizes; (void)n_in; (void)out_size; (void)ws_size;
    const float* x     = (const float*)d_in[0];
    const float* n1g   = (const float*)d_in[1];
    const float* n1b   = (const float*)d_in[2];
    const float* qkv_r = (const float*)d_in[3];
    const float* pr_w  = (const float*)d_in[4];
    const float* pr_b  = (const float*)d_in[5];
    const float* tab_r = (const float*)d_in[6];
    const float* qkv_a = (const float*)d_in[7];
    const float* pa_w  = (const float*)d_in[8];
    const float* pa_b  = (const float*)d_in[9];
    const float* tab_a = (const float*)d_in[10];
    const float* n2g   = (const float*)d_in[11];
    const float* n2b   = (const float*)d_in[12];
    const float* w1    = (const float*)d_in[13];
    const float* b1    = (const float*)d_in[14];
    const float* w2    = (const float*)d_in[15];
    const float* b2    = (const float*)d_in[16];

    char* ws = (char*)d_ws;
    ushort_t* wqkvT_r = (ushort_t*)(ws);              //  98304 B
    ushort_t* wqkvT_a = (ushort_t*)(ws + 98304);      //  98304 B
    ushort_t* wpT_r   = (ushort_t*)(ws + 196608);     //  32768 B
    ushort_t* wpT_a   = (ushort_t*)(ws + 229376);     //  32768 B
    ushort_t* w1p     = (ushort_t*)(ws + 262144);     // 540672 B  [16][64][264]
    ushort_t* w2p     = (ushort_t*)(ws + 802816);     // 589824 B  [16][256][72]
    ushort_t* bout    = (ushort_t*)(ws + 1392640);    // 33554432 B
    ushort_t* xn      = (ushort_t*)d_out;             // staged in d_out (dead before mlp_k)

    prep_k<<<1664, 256, 0, stream>>>(x, n1g, n1b, xn,
                                     qkv_r, wqkvT_r, qkv_a, wqkvT_a,
                                     pr_w, wpT_r, pa_w, wpT_a,
                                     w1, w1p, w2, w2p);
    attn_k<<<dim3(1024, 2), 256, 0, stream>>>(xn, wqkvT_r, wpT_r, pr_b, tab_r,
                                              wqkvT_a, wpT_a, pa_b, tab_a, bout);
    mlp_k<<<1024, 256, 0, stream>>>(x, bout, n2g, n2b, w1p, b1, w2p, b2, (float*)d_out);
}